// Round 14
// baseline (41.317 us; speedup 1.0000x reference)
//
#include <hip/hip_runtime.h>
#include <math.h>

#define CIN  32
#define COUT 32
#define BB   4
#define HH   80
#define WW   80
#define HW   (HH * WW)
#define NOUT (BB * COUT * HW)     // 819200
#define TH   16                   // output rows per block stripe
#define NT   320                  // 16 rows x 20 col-groups (4 cols each)

#define XPS  88                   // padded col stride (16B-aligned rows)
#define XPR  84                   // padded rows (80 + 4)
#define XPLANE (XPR * XPS)        // 7392
#define XPAD_SZ (BB * CIN * XPLANE)   // 946176 floats
#define WPAD_OFF 1048576              // float offset of padded weights in ws
#define WPAD_SZ (COUT * CIN * 28)     // 28672 floats
#define PART_OFF 2097152              // float offset of partials in ws

typedef float v4f __attribute__((ext_vector_type(4)));

__device__ __forceinline__ float max3f(float a, float b, float c) {
    float d;
    asm("v_max3_f32 %0, %1, %2, %3" : "=v"(d) : "v"(a), "v"(b), "v"(c));
    return d;
}

// Pads x into ws[0..XPAD_SZ) as [b*CIN+ci][84][88] with -inf halo (2 each side;
// cols 84..87 are alignment pad, also -inf). Pads w into ws[WPAD_OFF..) as
// [co*CIN+ci][28] (25 taps + 3 zeros) so weight rows are 16B-aligned.
__global__ __launch_bounds__(256) void pad_kernel(
    const float* __restrict__ x, const float* __restrict__ w,
    float* __restrict__ ws)
{
    int idx = blockIdx.x * 256 + threadIdx.x;
    int stride = gridDim.x * 256;
    for (int i = idx; i < XPAD_SZ; i += stride) {
        int c = i % XPS;
        int t = i / XPS;
        int r = t % XPR;
        int p = t / XPR;              // b*CIN + ci
        int gr = r - 2, gc = c - 2;
        float v = -INFINITY;
        if (gr >= 0 && gr < HH && gc >= 0 && gc < WW)
            v = x[(size_t)p * HW + gr * WW + gc];
        ws[i] = v;
    }
    for (int i = idx; i < WPAD_SZ; i += stride) {
        int q = i % 28, p = i / 28;
        ws[WPAD_OFF + i] = (q < 28 && q < 25) ? w[p * 25 + q] : 0.0f;
    }
}

// NO LDS, NO barriers. Thread = 1 row x 4 cols x co-pair x CP ci.
// x window read directly from the padded L2-resident copy (10 aligned
// global_load_dwordx4 per ci). Weights via block-uniform pointers -> s_load
// into SGPRs; adds are v_add_f32 v,s,v. Partials to ws[PART_OFF] (NP>1).
template<int NP>
__global__ __launch_bounds__(NT, 7) void semiconv_kernel(
    const float* __restrict__ ws,    // padded x + padded w
    const float* __restrict__ bias,
    float* __restrict__ dst)         // out (NP==1) or partials [NP][NOUT]
{
    constexpr int CP = CIN / NP;
    const int tid = threadIdx.x;
    const int bh  = blockIdx.x;               // 0..4 row stripe
    const int cp  = blockIdx.y;               // 0..15 co-pair
    const int zz  = blockIdx.z;               // b * NP + part
    const int b    = zz / NP;
    const int part = zz % NP;
    const int ci0  = part * CP;
    const int co0  = cp * 2;

    const int ty = tid / 20, tx = tid % 20;
    const int row = bh * TH + ty;             // output row == padded top row
    const int j0  = 4 * tx;                   // output col == padded left col

    const float* xp = ws + ((size_t)(b * CIN + ci0) * XPR + row) * XPS + j0;
    const float* wpA = ws + WPAD_OFF + ((size_t)(co0    ) * CIN + ci0) * 28;  // uniform
    const float* wpB = ws + WPAD_OFF + ((size_t)(co0 + 1) * CIN + ci0) * 28;  // uniform

    float sA[4] = {0.f, 0.f, 0.f, 0.f}, sB[4] = {0.f, 0.f, 0.f, 0.f};

    #pragma unroll 1
    for (int k = 0; k < CP; ++k) {
        // block-uniform weight loads -> SGPRs
        float wA[25], wB[25];
        #pragma unroll
        for (int q = 0; q < 25; ++q) { wA[q] = wpA[q]; wB[q] = wpB[q]; }

        // 10 independent aligned 16B loads (5 rows x 2)
        float xr[5][8];
        #pragma unroll
        for (int m = 0; m < 5; ++m) {
            v4f A = *(const v4f*)(xp + m * XPS);
            v4f C = *(const v4f*)(xp + m * XPS + 4);
            xr[m][0] = A.x; xr[m][1] = A.y; xr[m][2] = A.z; xr[m][3] = A.w;
            xr[m][4] = C.x; xr[m][5] = C.y; xr[m][6] = C.z; xr[m][7] = C.w;
        }

        float aA[4], aB[4];
        #pragma unroll
        for (int m = 0; m < 5; ++m) {
            #pragma unroll
            for (int j = 0; j < 4; ++j) {
                float t = max3f(xr[m][j]     + wA[5*m],
                                xr[m][j + 1] + wA[5*m + 1],
                                xr[m][j + 2] + wA[5*m + 2]);
                float u = fmaxf(xr[m][j + 3] + wA[5*m + 3],
                                xr[m][j + 4] + wA[5*m + 4]);
                aA[j] = (m == 0) ? fmaxf(t, u) : max3f(aA[j], t, u);
                t = max3f(xr[m][j]     + wB[5*m],
                          xr[m][j + 1] + wB[5*m + 1],
                          xr[m][j + 2] + wB[5*m + 2]);
                u = fmaxf(xr[m][j + 3] + wB[5*m + 3],
                          xr[m][j + 4] + wB[5*m + 4]);
                aB[j] = (m == 0) ? fmaxf(t, u) : max3f(aB[j], t, u);
            }
        }
        #pragma unroll
        for (int j = 0; j < 4; ++j) { sA[j] += aA[j]; sB[j] += aB[j]; }

        xp  += XPLANE;
        wpA += 28;
        wpB += 28;
    }

    size_t oiA = (((size_t)b * COUT + co0) * HH + row) * WW + j0;
    size_t oiB = oiA + (size_t)HW;
    v4f rA = {sA[0], sA[1], sA[2], sA[3]};
    v4f rB = {sB[0], sB[1], sB[2], sB[3]};
    float* o = dst;
    if (NP == 1) {
        float bcA = bias[co0], bcB = bias[co0 + 1];
        rA.x += bcA; rA.y += bcA; rA.z += bcA; rA.w += bcA;
        rB.x += bcB; rB.y += bcB; rB.z += bcB; rB.w += bcB;
    } else {
        o += (size_t)part * NOUT;
    }
    *(v4f*)(o + oiA) = rA;
    *(v4f*)(o + oiB) = rB;
}

template<int NP>
__global__ __launch_bounds__(256) void reduceN_kernel(
    const float* __restrict__ part, const float* __restrict__ bias,
    float* __restrict__ out)
{
    int i4 = blockIdx.x * 256 + threadIdx.x;        // 0..204799
    const float4* p = reinterpret_cast<const float4*>(part);
    float4 r = p[i4];
    #pragma unroll
    for (int q = 1; q < NP; ++q) {
        float4 t = p[i4 + (size_t)q * (NOUT / 4)];
        r.x += t.x; r.y += t.y; r.z += t.z; r.w += t.w;
    }
    int co = (i4 / (HW / 4)) & (COUT - 1);
    float bc = bias[co];
    r.x += bc; r.y += bc; r.z += bc; r.w += bc;
    reinterpret_cast<float4*>(out)[i4] = r;
}

// Last-resort correct path (only if ws is unexpectedly tiny).
__global__ __launch_bounds__(256) void naive_kernel(
    const float* __restrict__ x, const float* __restrict__ w,
    const float* __restrict__ bias, float* __restrict__ out)
{
    int o = blockIdx.x * 256 + threadIdx.x;
    if (o >= NOUT) return;
    int wcol = o % WW, h = (o / WW) % HH, co = (o / HW) % COUT, b = o / (COUT * HW);
    float sum = 0.f;
    for (int ci = 0; ci < CIN; ++ci) {
        float mx = -INFINITY;
        for (int m = 0; m < 5; ++m) {
            int gr = h + m - 2;
            if (gr < 0 || gr >= HH) continue;
            for (int n = 0; n < 5; ++n) {
                int gc = wcol + n - 2;
                if (gc < 0 || gc >= WW) continue;
                float v = x[((size_t)(b * CIN + ci)) * HW + gr * WW + gc]
                        + w[((size_t)(co * CIN + ci)) * 25 + m * 5 + n];
                mx = fmaxf(mx, v);
            }
        }
        sum += mx;
    }
    out[o] = sum + bias[co];
}

extern "C" void kernel_launch(void* const* d_in, const int* in_sizes, int n_in,
                              void* d_out, int out_size, void* d_ws, size_t ws_size,
                              hipStream_t stream) {
    const float* x    = (const float*)d_in[0];
    const float* w    = (const float*)d_in[1];
    const float* bias = (const float*)d_in[2];
    float* out        = (float*)d_out;
    float* ws         = (float*)d_ws;

    const size_t need4 = (size_t)(PART_OFF + 4ull * NOUT) * sizeof(float);  // ~21.5 MB
    const size_t need1 = (size_t)PART_OFF * sizeof(float);                  // ~8.4 MB

    if (ws_size >= need4) {
        pad_kernel<<<1024, 256, 0, stream>>>(x, w, ws);
        dim3 grid(HH / TH, COUT / 2, BB * 4);          // 5 x 16 x 16 = 1280 blocks
        semiconv_kernel<4><<<grid, NT, 0, stream>>>(ws, bias, ws + PART_OFF);
        reduceN_kernel<4><<<NOUT / 4 / 256, 256, 0, stream>>>(ws + PART_OFF, bias, out);
    } else if (ws_size >= need1) {
        pad_kernel<<<1024, 256, 0, stream>>>(x, w, ws);
        dim3 grid(HH / TH, COUT / 2, BB);              // 320 blocks, direct out
        semiconv_kernel<1><<<grid, NT, 0, stream>>>(ws, bias, out);
    } else {
        naive_kernel<<<(NOUT + 255) / 256, 256, 0, stream>>>(x, w, bias, out);
    }
}